// Round 2
// baseline (784.439 us; speedup 1.0000x reference)
//
#include <hip/hip_runtime.h>

#define DI __device__ __forceinline__

typedef __attribute__((ext_vector_type(8))) short short8;
typedef __attribute__((ext_vector_type(4))) float f32x4;

constexpr int THREADS = 512;           // 8 waves
constexpr int ROWS    = 16;            // batch rows per block (halved -> 2 blocks/CU)
constexpr int NBLK    = 8192 / ROWS;   // 512 blocks = 2 per CU
constexpr int PITCH   = 272;           // K=128 bf16 rows; 272%128==16 -> b128 reads conflict-free
constexpr int PITCH2  = 528;           // K=256 bf16 rows; 528%128==16 -> conflict-free
constexpr int SPITCH  = 256;           // staging pitch (conflicts don't matter there)

// ---- LDS layout (bytes), total 58112 -> 2 blocks/CU ----
constexpr int O_PAST  = 0;        // 25344 = 16*6*132*2 : past_l (encoder)
constexpr int O_PATCH = 25344;    // 5120  = 64 rows x 80B (4 steps x 16 rows)
constexpr int O_XALL  = 30464;    // 17408 = 64 rows x 272B
constexpr int O_H     = 47872;    // 2 x 4352 hidden-state double buffer
constexpr int HBUF    = 4352;     // 16 rows x 272
constexpr int O_FC3W  = 56576;    // 1536: fc3 weights f32
constexpr int LDS_TOTAL = 58112;
// staging aliases the past/patch/xall zone (0..47871); max single stage = 33792 (fc2)
constexpr int O_STAGE = 0;
// decoder aliases (patch/x_all dead during decoder steps)
constexpr int O_A1D   = 25344;    // 8448: a1 (16 x 528)
constexpr int O_A2D   = 33792;    // 2304: a2 (16 x 144)

// HW packed f32->bf16 (RNE), 1 instr; no builtin on gfx950 -> inline asm.
DI unsigned cvtpk2(float lo, float hi){
  unsigned r;
  asm("v_cvt_pk_bf16_f32 %0, %1, %2" : "=v"(r) : "v"(lo), "v"(hi));
  return r;
}
DI unsigned short f2bf(float f){ return (unsigned short)cvtpk2(f, f); }
DI float bf2f(unsigned short u){
  union { unsigned u; float f; } v; v.u = ((unsigned)u) << 16;
  return v.f;
}
DI float u2f_lo(unsigned u){ union { unsigned u; float f; } v; v.u = u << 16;        return v.f; }
DI float u2f_hi(unsigned u){ union { unsigned u; float f; } v; v.u = u & 0xffff0000u; return v.f; }
// rcp-based activations (v_rcp_f32, ~1 ulp); saturation correct (rcp(inf)=0).
DI float sigm(float x){ return __builtin_amdgcn_rcpf(1.f + __expf(-x)); }
DI float tanh_(float x){ return 2.f * __builtin_amdgcn_rcpf(1.f + __expf(-2.f * x)) - 1.f; }
DI f32x4 mfma16(short8 a, short8 b, f32x4 c){
  return __builtin_amdgcn_mfma_f32_16x16x32_bf16(a, b, c, 0, 0, 0);
}
DI uint2 pack4(f32x4 v){
  return make_uint2(cvtpk2(v[0], v[1]), cvtpk2(v[2], v[3]));
}
DI f32x4 unpack4(uint2 u){
  return (f32x4){u2f_lo(u.x), u2f_hi(u.x), u2f_lo(u.y), u2f_hi(u.y)};
}

// stage (nrows x 128) f32 -> bf16 LDS, pitch SPITCH
DI void stage_k128(char* dst, const float* __restrict__ src, int nrows, int tid){
  const int total = nrows * 32;
  for (int i = tid; i < total; i += THREADS){
    float4 v = ((const float4*)src)[i];
    int e = i << 2;
    int n = e >> 7, k = e & 127;
    *(uint2*)(dst + n * SPITCH + k * 2) = make_uint2(cvtpk2(v.x, v.y), cvtpk2(v.z, v.w));
  }
}
// stage (nrows x 256) f32 -> bf16 LDS, pitch 528
DI void stage_k256(char* dst, const float* __restrict__ src, int nrows, int tid){
  const int total = nrows * 64;
  for (int i = tid; i < total; i += THREADS){
    float4 v = ((const float4*)src)[i];
    int e = i << 2;
    int n = e >> 8, k = e & 255;
    *(uint2*)(dst + n * PITCH2 + k * 2) = make_uint2(cvtpk2(v.x, v.y), cvtpk2(v.z, v.w));
  }
}

__global__ void __launch_bounds__(THREADS, 4)
gru_fused(const float* __restrict__ past,
          const float* __restrict__ conv_w, const float* __restrict__ conv_b,
          const float* __restrict__ bn_gamma, const float* __restrict__ bn_beta,
          const float* __restrict__ bn_mean, const float* __restrict__ bn_var,
          const float* __restrict__ enc_wih, const float* __restrict__ enc_whh,
          const float* __restrict__ enc_bih, const float* __restrict__ enc_bhh,
          const float* __restrict__ dec_wih, const float* __restrict__ dec_whh,
          const float* __restrict__ dec_bih, const float* __restrict__ dec_bhh,
          const float* __restrict__ fc1_w, const float* __restrict__ fc1_b,
          const float* __restrict__ fc2_w, const float* __restrict__ fc2_b,
          const float* __restrict__ fc3_w, const float* __restrict__ fc3_b,
          float* __restrict__ out)
{
  extern __shared__ char smem[];
  const int tid  = threadIdx.x;
  const int lane = tid & 63, w = tid >> 6;        // wave w owns gate-col slice w*16..w*16+15
  const int l15  = lane & 15, quad = lane >> 4;
  const int b0   = blockIdx.x * ROWS;
  const int col  = w * 16 + l15;

  // ---- per-thread bias registers ----
  const float br_e  = enc_bih[col]       + enc_bhh[col];
  const float bz_e  = enc_bih[128 + col] + enc_bhh[128 + col];
  const float bin_e = enc_bih[256 + col];
  const float bhn_e = enc_bhh[256 + col];
  const float br_d  = dec_bih[col]       + dec_bhh[col];
  const float bz_d  = dec_bih[128 + col] + dec_bhh[128 + col];
  const float bin_d = dec_bih[256 + col];
  const float bhn_d = dec_bhh[256 + col];
  const float cb_t  = conv_b[col];
  const float s_bn  = bn_gamma[0] * rsqrtf(bn_var[0] + 1e-5f);
  const float o_bn  = bn_beta[0] - bn_mean[0] * s_bn;
  const float fb1a  = fc1_b[w * 32 + l15];
  const float fb1b  = fc1_b[w * 32 + 16 + l15];
  const float fb2   = fc2_b[(w & 3) * 16 + l15];

  // ---- zero h double buffer ----
  for (int i = tid; i < 2*HBUF/4; i += THREADS) ((unsigned*)(smem + O_H))[i] = 0u;

  // ---- stage encoder weights per gate (128 rows each), pull B-fragments ----
  short8 wf[3][4], wh[3][4];
  #pragma unroll
  for (int g = 0; g < 3; ++g){
    stage_k128(smem + O_STAGE, enc_wih + g*16384, 128, tid);
    __syncthreads();
    #pragma unroll
    for (int kt = 0; kt < 4; ++kt)
      wf[g][kt] = *(const short8*)(smem + O_STAGE + col*SPITCH + kt*64 + quad*16);
    __syncthreads();
  }
  #pragma unroll
  for (int g = 0; g < 3; ++g){
    stage_k128(smem + O_STAGE, enc_whh + g*16384, 128, tid);
    __syncthreads();
    #pragma unroll
    for (int kt = 0; kt < 4; ++kt)
      wh[g][kt] = *(const short8*)(smem + O_STAGE + col*SPITCH + kt*64 + quad*16);
    __syncthreads();
  }

  // ---- conv weights: cwT[oc][k=c*3+kk] bf16, 80B rows, K padded 18->32 ----
  for (int i = tid; i < 2560; i += THREADS) ((unsigned*)(smem + O_STAGE))[i] = 0u;
  __syncthreads();
  for (int i = tid; i < 2304; i += THREADS){
    int oc = i / 18, kk = i - oc * 18;
    *(unsigned short*)(smem + O_STAGE + oc*80 + kk*2) = f2bf(conv_w[i]);
  }
  __syncthreads();
  const short8 cwf = *(const short8*)(smem + O_STAGE + col*80 + quad*16);
  __syncthreads();

  // ---- past -> LDS bf16: past_l[m][c][tpos 0..131] (shift +1, zero padded) ----
  for (int i = tid; i < 6336; i += THREADS) ((unsigned*)(smem + O_PAST))[i] = 0u;
  __syncthreads();
  for (int i4 = tid; i4 < 3072; i4 += THREADS){
    int m = i4 / 192, rem = i4 - m*192, c = rem >> 5, t4 = (rem & 31) << 2;
    float4 v = *(const float4*)(past + (size_t)(b0 + m)*768 + c*128 + t4);
    unsigned short* dst = (unsigned short*)(smem + O_PAST + ((m*6 + c)*132 + t4 + 1)*2);
    dst[0] = f2bf(v.x); dst[1] = f2bf(v.y); dst[2] = f2bf(v.z); dst[3] = f2bf(v.w);
  }
  for (int i = tid; i < 384; i += THREADS) ((float*)(smem + O_FC3W))[i] = fc3_w[i];
  __syncthreads();

  // patch-build constants: 288 entries (16 rows x 18); tid<288 handles one
  const int e0 = tid;
  const int m0 = e0 / 18, r0 = e0 - m0*18, c0 = r0 / 3, k0 = r0 - c0*3;

  // build patch_all rows tc*16+m for steps t0..t0+3 (one entry; 16-row step stride = 1280B)
  auto patch_entry = [&](int t0, int m, int r18, int c, int k){
    int base = (m*6 + c)*132 + t0 + k;            // short index into past_l
    const unsigned* pl = (const unsigned*)(smem + O_PAST);
    unsigned w0 = pl[base >> 1], w1 = pl[(base >> 1) + 1], w2 = pl[(base >> 1) + 2];
    int sh = (base & 1) * 16;
    unsigned long long lo = (unsigned long long)w0 | ((unsigned long long)w1 << 32);
    unsigned long long hi = (unsigned long long)w1 | ((unsigned long long)w2 << 32);
    unsigned a01 = (unsigned)(lo >> sh);          // shorts t0+k, t0+k+1
    unsigned a23 = (unsigned)(hi >> sh);          // shorts t0+k+2, t0+k+3
    char* pb = smem + O_PATCH + m*80 + r18*2;
    *(unsigned short*)(pb)          = (unsigned short)(a01 & 0xffff);
    *(unsigned short*)(pb + 1280)   = (unsigned short)(a01 >> 16);
    *(unsigned short*)(pb + 2560)   = (unsigned short)(a23 & 0xffff);
    *(unsigned short*)(pb + 3840)   = (unsigned short)(a23 >> 16);
  };

  // ---- accumulator/state registers ----
  uint2 gi_pk[4][3];                    // packed-bf16 gi for 4 steps: [tc][gate]
  float hreg[4];
  #pragma unroll
  for (int i = 0; i < 4; ++i) hreg[i] = 0.f;

  // ================= encoder: 32 chunks of (phase A + 4 light steps) =================
  for (int chunk = 0; chunk < 32; ++chunk){
    const int t0 = chunk * 4;
    // ---- phase A1: build 4 patches (reads past_l, writes patch_all) ----
    if (e0 < 288) patch_entry(t0, m0, r0, c0, k0);
    __syncthreads();
    // ---- phase A2: conv as M=64 GEMM + bias/relu/bn -> x_all ----
    #pragma unroll
    for (int mt8 = 0; mt8 < 4; ++mt8){
      short8 pa = *(const short8*)(smem + O_PATCH + (mt8*16 + l15)*80 + quad*16);
      f32x4 cc = (f32x4){0.f,0.f,0.f,0.f};
      cc = mfma16(pa, cwf, cc);
      #pragma unroll
      for (int r = 0; r < 4; ++r){
        int mrow = mt8*16 + quad*4 + r;
        float vx = s_bn * fmaxf(cc[r] + cb_t, 0.f) + o_bn;
        *(unsigned short*)(smem + O_XALL + mrow*PITCH + col*2) = f2bf(vx);
      }
    }
    __syncthreads();
    // ---- phase A3: gi GEMM for 4 steps (M=64), pack to bf16 regs ----
    #pragma unroll
    for (int tc = 0; tc < 4; ++tc){
      short8 a[4];
      #pragma unroll
      for (int kt = 0; kt < 4; ++kt)
        a[kt] = *(const short8*)(smem + O_XALL + (tc*16 + l15)*PITCH + kt*64 + quad*16);
      f32x4 g0 = (f32x4){0.f,0.f,0.f,0.f}, g1 = g0, g2 = g0;
      #pragma unroll
      for (int kt = 0; kt < 4; ++kt){
        g0 = mfma16(a[kt], wf[0][kt], g0);
        g1 = mfma16(a[kt], wf[1][kt], g1);
        g2 = mfma16(a[kt], wf[2][kt], g2);
      }
      gi_pk[tc][0] = pack4(g0);
      gi_pk[tc][1] = pack4(g1);
      gi_pk[tc][2] = pack4(g2);
    }
    // x_all reads protected by next chunk's A1 barrier

    // ---- 4 recurrent steps: gh GEMM + gate math, 1 barrier each ----
    #pragma unroll
    for (int tc = 0; tc < 4; ++tc){
      const int t = t0 + tc;
      const char* hr = smem + O_H + (t & 1) * HBUF;
      char*       hw = smem + O_H + ((t + 1) & 1) * HBUF;
      f32x4 accr = unpack4(gi_pk[tc][0]);
      f32x4 accz = unpack4(gi_pk[tc][1]);
      f32x4 gin  = unpack4(gi_pk[tc][2]);
      f32x4 accn2 = (f32x4){0.f,0.f,0.f,0.f};
      short8 ha[4];
      #pragma unroll
      for (int kt = 0; kt < 4; ++kt)
        ha[kt] = *(const short8*)(hr + l15*PITCH + kt*64 + quad*16);
      #pragma unroll
      for (int kt = 0; kt < 4; ++kt){
        accr  = mfma16(ha[kt], wh[0][kt], accr);
        accz  = mfma16(ha[kt], wh[1][kt], accz);
        accn2 = mfma16(ha[kt], wh[2][kt], accn2);
      }
      #pragma unroll
      for (int r = 0; r < 4; ++r){
        float rg = sigm(accr[r] + br_e);
        float zg = sigm(accz[r] + bz_e);
        float ng = tanh_(gin[r] + bin_e + rg*(accn2[r] + bhn_e));
        hreg[r] = ng + zg*(hreg[r] - ng);
      }
      #pragma unroll
      for (int r = 0; r < 4; ++r)
        *(unsigned short*)(hw + (quad*4 + r)*PITCH + col*2) = f2bf(hreg[r]);
      __syncthreads();   // h(t+1) visible; h(t) reads complete
    }
  }
  // after t=127: h_enc lives in hbuf[0] (and hreg)

  // ================= decoder init =================
  // dec_wih frags (per-gate staging) + gi0 = h_enc @ dec_wih^T
  #pragma unroll
  for (int g = 0; g < 3; ++g){
    stage_k128(smem + O_STAGE, dec_wih + g*16384, 128, tid);
    __syncthreads();
    #pragma unroll
    for (int kt = 0; kt < 4; ++kt)
      wf[g][kt] = *(const short8*)(smem + O_STAGE + col*SPITCH + kt*64 + quad*16);
    __syncthreads();
  }
  f32x4 gi0r, gi0z, gi0n;
  {
    short8 hea[4];
    #pragma unroll
    for (int kt = 0; kt < 4; ++kt)
      hea[kt] = *(const short8*)(smem + O_H + l15*PITCH + kt*64 + quad*16);
    gi0r = (f32x4){0.f,0.f,0.f,0.f}; gi0z = gi0r; gi0n = gi0r;
    #pragma unroll
    for (int kt = 0; kt < 4; ++kt){
      gi0r = mfma16(hea[kt], wf[0][kt], gi0r);
      gi0z = mfma16(hea[kt], wf[1][kt], gi0z);
      gi0n = mfma16(hea[kt], wf[2][kt], gi0n);
    }
  }
  __syncthreads();
  #pragma unroll
  for (int g = 0; g < 3; ++g){
    stage_k128(smem + O_STAGE, dec_whh + g*16384, 128, tid);
    __syncthreads();
    #pragma unroll
    for (int kt = 0; kt < 4; ++kt)
      wh[g][kt] = *(const short8*)(smem + O_STAGE + col*SPITCH + kt*64 + quad*16);
    __syncthreads();
  }
  // fc1 B-frags: two 128-row halves (waves 0-3 then 4-7)
  short8 f1f[2][4], f2f[8];
  stage_k128(smem + O_STAGE, fc1_w, 128, tid);
  __syncthreads();
  if (w < 4){
    #pragma unroll
    for (int j = 0; j < 2; ++j)
      #pragma unroll
      for (int kt = 0; kt < 4; ++kt)
        f1f[j][kt] = *(const short8*)(smem + O_STAGE + (w*32 + j*16 + l15)*SPITCH + kt*64 + quad*16);
  }
  __syncthreads();
  stage_k128(smem + O_STAGE, fc1_w + 16384, 128, tid);
  __syncthreads();
  if (w >= 4){
    #pragma unroll
    for (int j = 0; j < 2; ++j)
      #pragma unroll
      for (int kt = 0; kt < 4; ++kt)
        f1f[j][kt] = *(const short8*)(smem + O_STAGE + ((w-4)*32 + j*16 + l15)*SPITCH + kt*64 + quad*16);
  }
  __syncthreads();
  stage_k256(smem + O_STAGE, fc2_w, 64, tid);
  __syncthreads();
  #pragma unroll
  for (int kt = 0; kt < 8; ++kt)
    f2f[kt] = *(const short8*)(smem + O_STAGE + ((w & 3)*16 + l15)*PITCH2 + kt*64 + quad*16);
  __syncthreads();
  // zero decoder h0 (buffer 1), reset hreg, present init
  for (int i = tid; i < HBUF/4; i += THREADS) ((unsigned*)(smem + O_H + HBUF))[i] = 0u;
  #pragma unroll
  for (int i = 0; i < 4; ++i) hreg[i] = 0.f;
  const int prow = tid / 6, pcol = tid - prow*6;
  float present = 0.f, fb3 = 0.f;
  if (tid < 96){
    present = past[(size_t)(b0 + prow)*768 + pcol*128 + 127];
    fb3 = fc3_b[pcol];
  }
  __syncthreads();

  // ================= decoder: 30 steps, 3 barriers each =================
  for (int s = 0; s < 30; ++s){
    const char* hr = smem + O_H + (1 - (s & 1)) * HBUF;
    char*       hw = smem + O_H + (s & 1) * HBUF;
    f32x4 accr, accz, gin;
    if (s == 0){ accr = gi0r; accz = gi0z; gin = gi0n; }
    else       { accr = (f32x4){0.f,0.f,0.f,0.f}; accz = accr; gin = accr; }
    f32x4 accn2 = (f32x4){0.f,0.f,0.f,0.f};
    {
      short8 ha[4];
      #pragma unroll
      for (int kt = 0; kt < 4; ++kt)
        ha[kt] = *(const short8*)(hr + l15*PITCH + kt*64 + quad*16);
      #pragma unroll
      for (int kt = 0; kt < 4; ++kt){
        accr  = mfma16(ha[kt], wh[0][kt], accr);
        accz  = mfma16(ha[kt], wh[1][kt], accz);
        accn2 = mfma16(ha[kt], wh[2][kt], accn2);
      }
    }
    #pragma unroll
    for (int r = 0; r < 4; ++r){
      float rg = sigm(accr[r] + br_d);
      float zg = sigm(accz[r] + bz_d);
      float ng = tanh_(gin[r] + bin_d + rg*(accn2[r] + bhn_d));
      hreg[r] = ng + zg*(hreg[r] - ng);
    }
    #pragma unroll
    for (int r = 0; r < 4; ++r)
      *(unsigned short*)(hw + (quad*4 + r)*PITCH + col*2) = f2bf(hreg[r]);
    __syncthreads();   // D1: h(s+1) visible

    // fc1: (16x128)@(128x256) + relu -> a1 (B-frags in regs)
    {
      short8 hf[4];
      #pragma unroll
      for (int kt = 0; kt < 4; ++kt)
        hf[kt] = *(const short8*)(hw + l15*PITCH + kt*64 + quad*16);
      f32x4 a1a[2];
      #pragma unroll
      for (int j = 0; j < 2; ++j) a1a[j] = (f32x4){0.f,0.f,0.f,0.f};
      #pragma unroll
      for (int j = 0; j < 2; ++j)
        #pragma unroll
        for (int kt = 0; kt < 4; ++kt)
          a1a[j] = mfma16(hf[kt], f1f[j][kt], a1a[j]);
      #pragma unroll
      for (int j = 0; j < 2; ++j){
        float bb = j ? fb1b : fb1a;
        #pragma unroll
        for (int r = 0; r < 4; ++r)
          *(unsigned short*)(smem + O_A1D + (quad*4 + r)*PITCH2 +
                             (w*32 + j*16 + l15)*2) = f2bf(fmaxf(a1a[j][r] + bb, 0.f));
      }
    }
    __syncthreads();   // D2: a1 visible

    // fc2: (16x256)@(256x64) -> a2 ; waves 0-3 each own one 16-col n-tile
    if (w < 4){
      f32x4 a2a = (f32x4){0.f,0.f,0.f,0.f};
      #pragma unroll
      for (int kt = 0; kt < 8; ++kt){
        short8 a = *(const short8*)(smem + O_A1D + l15*PITCH2 + kt*64 + quad*16);
        a2a = mfma16(a, f2f[kt], a2a);
      }
      #pragma unroll
      for (int r = 0; r < 4; ++r)
        *(unsigned short*)(smem + O_A2D + (quad*4 + r)*144 + (w*16 + l15)*2) =
            f2bf(a2a[r] + fb2);
    }
    __syncthreads();   // D3: a2 visible

    // fc3 (6x64, VALU) + present accumulate + store
    if (tid < 96){
      float o = fb3;
      const float* w3 = (const float*)(smem + O_FC3W) + pcol*64;
      #pragma unroll
      for (int kc = 0; kc < 8; ++kc){
        short8 av = *(const short8*)(smem + O_A2D + prow*144 + kc*16);
        #pragma unroll
        for (int j = 0; j < 8; ++j)
          o += bf2f((unsigned short)av[j]) * w3[kc*8 + j];
      }
      present += o;
      out[(size_t)(b0 + prow)*180 + pcol*30 + s] = present;   // (B, 6, 30)
    }
    // fc3's a2 reads are protected by next step's D1+D2 barriers
  }
}

extern "C" void kernel_launch(void* const* d_in, const int* in_sizes, int n_in,
                              void* d_out, int out_size, void* d_ws, size_t ws_size,
                              hipStream_t stream) {
  (void)in_sizes; (void)n_in; (void)out_size; (void)d_ws; (void)ws_size;
  const float* past     = (const float*)d_in[0];
  const float* conv_w   = (const float*)d_in[1];
  const float* conv_b   = (const float*)d_in[2];
  const float* bn_gamma = (const float*)d_in[3];
  const float* bn_beta  = (const float*)d_in[4];
  const float* bn_mean  = (const float*)d_in[5];
  const float* bn_var   = (const float*)d_in[6];
  const float* enc_wih  = (const float*)d_in[7];
  const float* enc_whh  = (const float*)d_in[8];
  const float* enc_bih  = (const float*)d_in[9];
  const float* enc_bhh  = (const float*)d_in[10];
  const float* dec_wih  = (const float*)d_in[11];
  const float* dec_whh  = (const float*)d_in[12];
  const float* dec_bih  = (const float*)d_in[13];
  const float* dec_bhh  = (const float*)d_in[14];
  const float* fc1_w    = (const float*)d_in[15];
  const float* fc1_b    = (const float*)d_in[16];
  const float* fc2_w    = (const float*)d_in[17];
  const float* fc2_b    = (const float*)d_in[18];
  const float* fc3_w    = (const float*)d_in[19];
  const float* fc3_b    = (const float*)d_in[20];

  hipFuncSetAttribute((const void*)gru_fused,
                      hipFuncAttributeMaxDynamicSharedMemorySize, LDS_TOTAL);

  gru_fused<<<NBLK, THREADS, LDS_TOTAL, stream>>>(
      past, conv_w, conv_b, bn_gamma, bn_beta, bn_mean, bn_var,
      enc_wih, enc_whh, enc_bih, enc_bhh,
      dec_wih, dec_whh, dec_bih, dec_bhh,
      fc1_w, fc1_b, fc2_w, fc2_b, fc3_w, fc3_b,
      (float*)d_out);
}

// Round 3
// 471.948 us; speedup vs baseline: 1.6621x; 1.6621x over previous
//
#include <hip/hip_runtime.h>

#define DI __device__ __forceinline__

typedef __attribute__((ext_vector_type(8))) short short8;
typedef __attribute__((ext_vector_type(4))) float f32x4;

constexpr int THREADS = 512;           // 8 waves
constexpr int ROWS    = 32;            // batch rows per block
constexpr int NBLK    = 8192 / ROWS;   // 256 blocks = 256 CUs
constexpr int PITCH   = 272;           // K=128 bf16 rows; 272%128==16 -> b128 reads conflict-free
constexpr int PITCH2  = 528;           // K=256 bf16 rows; 528%128==16 -> conflict-free
constexpr int SPITCH  = 256;           // one-time staging pitch (conflicts don't matter there)

// ---- LDS layout (bytes) ----
constexpr int O_STAGE = 0;        // 98304 = 384*256: staging; then past_l (50688) in encoder
constexpr int O_PATCH = 98304;    // 10240: patch_all 128 rows x 80B (4 steps x 32 rows)
constexpr int O_XALL  = 108544;   // 34816: x_all 128 rows x 272B (4 steps x 32 rows)
constexpr int O_H     = 143360;   // 2 x 8704 hidden-state double buffer
constexpr int HBUF    = 8704;
constexpr int O_FC3W  = 160768;   // 1536: fc3 weights f32
constexpr int LDS_TOTAL = 162304; // <= 163840
// decoder aliases (stage/patch/x_all dead during decoder steps)
constexpr int O_A1D   = 98304;    // 16896: a1 (32 x 528)
constexpr int O_A2D   = 115200;   // 4608:  a2 (32 x 144)

// HW packed f32->bf16 (RNE), 1 instr; no builtin on gfx950 -> inline asm.
DI unsigned cvtpk2(float lo, float hi){
  unsigned r;
  asm("v_cvt_pk_bf16_f32 %0, %1, %2" : "=v"(r) : "v"(lo), "v"(hi));
  return r;
}
DI unsigned short f2bf(float f){ return (unsigned short)cvtpk2(f, f); }
DI float bf2f(unsigned short u){
  union { unsigned u; float f; } v; v.u = ((unsigned)u) << 16;
  return v.f;
}
DI float u2f_lo(unsigned u){ union { unsigned u; float f; } v; v.u = u << 16;        return v.f; }
DI float u2f_hi(unsigned u){ union { unsigned u; float f; } v; v.u = u & 0xffff0000u; return v.f; }
// rcp-based activations (v_rcp_f32, ~1 ulp); saturation correct (rcp(inf)=0).
DI float sigm(float x){ return __builtin_amdgcn_rcpf(1.f + __expf(-x)); }
DI float tanh_(float x){ return 2.f * __builtin_amdgcn_rcpf(1.f + __expf(-2.f * x)) - 1.f; }
DI f32x4 mfma16(short8 a, short8 b, f32x4 c){
  return __builtin_amdgcn_mfma_f32_16x16x32_bf16(a, b, c, 0, 0, 0);
}
DI uint2 pack4(f32x4 v){
  return make_uint2(cvtpk2(v[0], v[1]), cvtpk2(v[2], v[3]));
}
DI f32x4 unpack4(uint2 u){
  return (f32x4){u2f_lo(u.x), u2f_hi(u.x), u2f_lo(u.y), u2f_hi(u.y)};
}

// one-time: stage (nrows x 128) f32 -> bf16 LDS, pitch SPITCH
DI void stage_k128(char* dst, const float* __restrict__ src, int nrows, int tid){
  const int total = nrows * 32;
  for (int i = tid; i < total; i += THREADS){
    float4 v = ((const float4*)src)[i];
    int e = i << 2;
    int n = e >> 7, k = e & 127;
    *(uint2*)(dst + n * SPITCH + k * 2) = make_uint2(cvtpk2(v.x, v.y), cvtpk2(v.z, v.w));
  }
}
// one-time: stage (nrows x 256) f32 -> bf16 LDS, pitch 528
DI void stage_k256(char* dst, const float* __restrict__ src, int nrows, int tid){
  const int total = nrows * 64;
  for (int i = tid; i < total; i += THREADS){
    float4 v = ((const float4*)src)[i];
    int e = i << 2;
    int n = e >> 8, k = e & 255;
    *(uint2*)(dst + n * PITCH2 + k * 2) = make_uint2(cvtpk2(v.x, v.y), cvtpk2(v.z, v.w));
  }
}

__global__ void __launch_bounds__(THREADS, 2)
gru_fused(const float* __restrict__ past,
          const float* __restrict__ conv_w, const float* __restrict__ conv_b,
          const float* __restrict__ bn_gamma, const float* __restrict__ bn_beta,
          const float* __restrict__ bn_mean, const float* __restrict__ bn_var,
          const float* __restrict__ enc_wih, const float* __restrict__ enc_whh,
          const float* __restrict__ enc_bih, const float* __restrict__ enc_bhh,
          const float* __restrict__ dec_wih, const float* __restrict__ dec_whh,
          const float* __restrict__ dec_bih, const float* __restrict__ dec_bhh,
          const float* __restrict__ fc1_w, const float* __restrict__ fc1_b,
          const float* __restrict__ fc2_w, const float* __restrict__ fc2_b,
          const float* __restrict__ fc3_w, const float* __restrict__ fc3_b,
          float* __restrict__ out)
{
  extern __shared__ char smem[];
  const int tid  = threadIdx.x;
  const int lane = tid & 63, w = tid >> 6;        // wave w owns gate-col slice w*16..w*16+15
  const int l15  = lane & 15, quad = lane >> 4;
  const int b0   = blockIdx.x * ROWS;
  const int col  = w * 16 + l15;

  // ---- per-thread bias registers ----
  const float br_e  = enc_bih[col]       + enc_bhh[col];
  const float bz_e  = enc_bih[128 + col] + enc_bhh[128 + col];
  const float bin_e = enc_bih[256 + col];
  const float bhn_e = enc_bhh[256 + col];
  const float br_d  = dec_bih[col]       + dec_bhh[col];
  const float bz_d  = dec_bih[128 + col] + dec_bhh[128 + col];
  const float bin_d = dec_bih[256 + col];
  const float bhn_d = dec_bhh[256 + col];
  const float cb_t  = conv_b[col];
  const float s_bn  = bn_gamma[0] * rsqrtf(bn_var[0] + 1e-5f);
  const float o_bn  = bn_beta[0] - bn_mean[0] * s_bn;
  const float fb1a  = fc1_b[w * 32 + l15];
  const float fb1b  = fc1_b[w * 32 + 16 + l15];
  const int   mt2   = w & 1, nt2 = w >> 1;        // fc2 decomposition
  const float fb2   = fc2_b[nt2 * 16 + l15];

  // ---- zero h double buffer ----
  for (int i = tid; i < 2*HBUF/4; i += THREADS) ((unsigned*)(smem + O_H))[i] = 0u;

  // ---- stage encoder weights once, pull B-fragments to registers ----
  short8 wf[3][4], wh[3][4];
  stage_k128(smem + O_STAGE, enc_wih, 384, tid);
  __syncthreads();
  #pragma unroll
  for (int g = 0; g < 3; ++g)
    #pragma unroll
    for (int kt = 0; kt < 4; ++kt)
      wf[g][kt] = *(const short8*)(smem + O_STAGE + (g*128 + col)*SPITCH + kt*64 + quad*16);
  __syncthreads();
  stage_k128(smem + O_STAGE, enc_whh, 384, tid);
  __syncthreads();
  #pragma unroll
  for (int g = 0; g < 3; ++g)
    #pragma unroll
    for (int kt = 0; kt < 4; ++kt)
      wh[g][kt] = *(const short8*)(smem + O_STAGE + (g*128 + col)*SPITCH + kt*64 + quad*16);
  __syncthreads();

  // ---- conv weights: cwT[oc][k=c*3+kk] bf16, 80B rows, K padded 18->32 ----
  for (int i = tid; i < 2560; i += THREADS) ((unsigned*)(smem + O_STAGE))[i] = 0u;
  __syncthreads();
  for (int i = tid; i < 2304; i += THREADS){
    int oc = i / 18, kk = i - oc * 18;
    *(unsigned short*)(smem + O_STAGE + oc*80 + kk*2) = f2bf(conv_w[i]);
  }
  __syncthreads();
  const short8 cwf = *(const short8*)(smem + O_STAGE + col*80 + quad*16);
  __syncthreads();

  // ---- past -> LDS bf16: past_l[m][c][tpos 0..131] (shift +1, zero padded) ----
  for (int i = tid; i < 12672; i += THREADS) ((unsigned*)(smem + O_STAGE))[i] = 0u;
  __syncthreads();
  for (int i4 = tid; i4 < 6144; i4 += THREADS){
    int m = i4 / 192, rem = i4 - m*192, c = rem >> 5, t4 = (rem & 31) << 2;
    float4 v = *(const float4*)(past + (size_t)(b0 + m)*768 + c*128 + t4);
    unsigned short* dst = (unsigned short*)(smem + O_STAGE + ((m*6 + c)*132 + t4 + 1)*2);
    dst[0] = f2bf(v.x); dst[1] = f2bf(v.y); dst[2] = f2bf(v.z); dst[3] = f2bf(v.w);
  }
  for (int i = tid; i < 384; i += THREADS) ((float*)(smem + O_FC3W))[i] = fc3_w[i];
  __syncthreads();

  // patch-build constants: entry e -> (m, r18=(c,kk)); each thread covers e0 (+e1 if tid<64)
  const int e0 = tid;
  const int m0 = e0 / 18, r0 = e0 - m0*18, c0 = r0 / 3, k0 = r0 - c0*3;
  const int e1 = tid + 512;
  const int m1 = e1 / 18, r1 = e1 - m1*18, c1 = r1 / 3, k1 = r1 - c1*3;

  // build patch_all rows tc*32+m for steps t0..t0+3 (one entry)
  auto patch_entry = [&](int t0, int m, int r18, int c, int k){
    int base = (m*6 + c)*132 + t0 + k;            // short index into past_l
    const unsigned* pl = (const unsigned*)(smem + O_STAGE);
    unsigned w0 = pl[base >> 1], w1 = pl[(base >> 1) + 1], w2 = pl[(base >> 1) + 2];
    int sh = (base & 1) * 16;
    unsigned long long lo = (unsigned long long)w0 | ((unsigned long long)w1 << 32);
    unsigned long long hi = (unsigned long long)w1 | ((unsigned long long)w2 << 32);
    unsigned a01 = (unsigned)(lo >> sh);          // shorts t0+k, t0+k+1
    unsigned a23 = (unsigned)(hi >> sh);          // shorts t0+k+2, t0+k+3
    char* pb = smem + O_PATCH + m*80 + r18*2;
    *(unsigned short*)(pb)          = (unsigned short)(a01 & 0xffff);
    *(unsigned short*)(pb + 2560)   = (unsigned short)(a01 >> 16);
    *(unsigned short*)(pb + 5120)   = (unsigned short)(a23 & 0xffff);
    *(unsigned short*)(pb + 7680)   = (unsigned short)(a23 >> 16);
  };
  auto patchA1 = [&](int t0){
    patch_entry(t0, m0, r0, c0, k0);
    if (e1 < 576) patch_entry(t0, m1, r1, c1, k1);
  };

  // ---- accumulator/state registers ----
  uint2 gi_pk[4][2][3];                 // packed-bf16 gi ring for 4 steps: [tc][mt][gate]
  float hreg[8];
  #pragma unroll
  for (int i = 0; i < 8; ++i) hreg[i] = 0.f;

  // A2: conv as M=128 GEMM + bias/relu/bn -> x_all (reads patch, overwrites x_all)
  auto conv_block = [&](){
    #pragma unroll
    for (int mt8 = 0; mt8 < 8; ++mt8){
      short8 pa = *(const short8*)(smem + O_PATCH + (mt8*16 + l15)*80 + quad*16);
      f32x4 cc = (f32x4){0.f,0.f,0.f,0.f};
      cc = mfma16(pa, cwf, cc);
      #pragma unroll
      for (int r = 0; r < 4; ++r){
        int mrow = mt8*16 + quad*4 + r;
        float vx = s_bn * fmaxf(cc[r] + cb_t, 0.f) + o_bn;
        *(unsigned short*)(smem + O_XALL + mrow*PITCH + col*2) = f2bf(vx);
      }
    }
  };
  // A3 unit: gi for (tc, mt) from x_all -> gi_pk slot
  auto gi_unit = [&](int tc, int mt){
    short8 a[4];
    #pragma unroll
    for (int kt = 0; kt < 4; ++kt)
      a[kt] = *(const short8*)(smem + O_XALL + ((tc*2 + mt)*16 + l15)*PITCH + kt*64 + quad*16);
    f32x4 g0 = (f32x4){0.f,0.f,0.f,0.f}, g1 = g0, g2 = g0;
    #pragma unroll
    for (int kt = 0; kt < 4; ++kt){
      g0 = mfma16(a[kt], wf[0][kt], g0);
      g1 = mfma16(a[kt], wf[1][kt], g1);
      g2 = mfma16(a[kt], wf[2][kt], g2);
    }
    gi_pk[tc][mt][0] = pack4(g0);
    gi_pk[tc][mt][1] = pack4(g1);
    gi_pk[tc][mt][2] = pack4(g2);
  };
  // one recurrent step (consumes gi_pk[t&3]; no barrier inside)
  auto step_body = [&](int t){
    const int tc = t & 3;
    const char* hr = smem + O_H + (t & 1) * HBUF;
    char*       hw = smem + O_H + ((t + 1) & 1) * HBUF;
    f32x4 accr[2], accz[2], accn2[2], gin[2];
    #pragma unroll
    for (int mt = 0; mt < 2; ++mt){
      accr[mt]  = unpack4(gi_pk[tc][mt][0]);
      accz[mt]  = unpack4(gi_pk[tc][mt][1]);
      gin[mt]   = unpack4(gi_pk[tc][mt][2]);
      accn2[mt] = (f32x4){0.f,0.f,0.f,0.f};
    }
    short8 ha[2][4];
    #pragma unroll
    for (int mt = 0; mt < 2; ++mt)
      #pragma unroll
      for (int kt = 0; kt < 4; ++kt)
        ha[mt][kt] = *(const short8*)(hr + (mt*16 + l15)*PITCH + kt*64 + quad*16);
    #pragma unroll
    for (int mt = 0; mt < 2; ++mt)
      #pragma unroll
      for (int kt = 0; kt < 4; ++kt){
        accr[mt]  = mfma16(ha[mt][kt], wh[0][kt], accr[mt]);
        accz[mt]  = mfma16(ha[mt][kt], wh[1][kt], accz[mt]);
        accn2[mt] = mfma16(ha[mt][kt], wh[2][kt], accn2[mt]);
      }
    #pragma unroll
    for (int mt = 0; mt < 2; ++mt)
      #pragma unroll
      for (int r = 0; r < 4; ++r){
        float rg = sigm(accr[mt][r] + br_e);
        float zg = sigm(accz[mt][r] + bz_e);
        float ng = tanh_(gin[mt][r] + bin_e + rg*(accn2[mt][r] + bhn_e));
        hreg[mt*4 + r] = ng + zg*(hreg[mt*4 + r] - ng);
      }
    #pragma unroll
    for (int mt = 0; mt < 2; ++mt)
      #pragma unroll
      for (int r = 0; r < 4; ++r)
        *(unsigned short*)(hw + (mt*16 + quad*4 + r)*PITCH + col*2) = f2bf(hreg[mt*4 + r]);
  };

  // ================= encoder: software-pipelined =================
  // Prologue: build patch(0), conv(0), gi(0,*), build patch(1)
  patchA1(0);
  __syncthreads();
  conv_block();
  __syncthreads();
  #pragma unroll
  for (int tc = 0; tc < 4; ++tc){ gi_unit(tc, 0); gi_unit(tc, 1); }
  patchA1(4);        // safe: all patch reads (conv of chunk 0) completed before last barrier
  __syncthreads();

  // Main loop: chunk c consumes gi(c) while producing x_all/gi for c+1 and patch for c+2.
  // Invariants (each produce/consume pair separated by a step barrier):
  //   x_all: written by conv_block at step0(c) [holds c+1], read at steps1-3(c), next write step0(c+1)
  //   patch: written by patchA1 at step3(c) [holds c+2], read by conv_block at step0(c+1)
  //   gi_pk[tc]: consumed (regs) at step tc, refilled with gi(c+1,tc) at/after the same step
  for (int c = 0; c < 32; ++c){
    const int t0 = c * 4;
    const bool prod = (c < 31);
    step_body(t0 + 0);
    if (prod) conv_block();                       // x_all <- chunk c+1
    __syncthreads();
    step_body(t0 + 1);
    if (prod){ gi_unit(0,0); gi_unit(0,1); gi_unit(1,0); }
    __syncthreads();
    step_body(t0 + 2);
    if (prod){ gi_unit(1,1); gi_unit(2,0); gi_unit(2,1); }
    __syncthreads();
    step_body(t0 + 3);
    if (prod){ gi_unit(3,0); gi_unit(3,1); if (c < 30) patchA1(t0 + 8); }
    __syncthreads();
  }
  // after t=127: h_enc lives in hbuf[0] (and hreg)

  // ================= decoder init =================
  // dec_wih frags + gi0 = h_enc @ dec_wih^T
  stage_k128(smem + O_STAGE, dec_wih, 384, tid);
  __syncthreads();
  #pragma unroll
  for (int g = 0; g < 3; ++g)
    #pragma unroll
    for (int kt = 0; kt < 4; ++kt)
      wf[g][kt] = *(const short8*)(smem + O_STAGE + (g*128 + col)*SPITCH + kt*64 + quad*16);
  f32x4 gi0r[2], gi0z[2], gi0n[2];
  {
    short8 hea[2][4];
    #pragma unroll
    for (int mt = 0; mt < 2; ++mt)
      #pragma unroll
      for (int kt = 0; kt < 4; ++kt)
        hea[mt][kt] = *(const short8*)(smem + O_H + (mt*16 + l15)*PITCH + kt*64 + quad*16);
    #pragma unroll
    for (int mt = 0; mt < 2; ++mt){
      gi0r[mt] = (f32x4){0.f,0.f,0.f,0.f}; gi0z[mt] = gi0r[mt]; gi0n[mt] = gi0r[mt];
      #pragma unroll
      for (int kt = 0; kt < 4; ++kt){
        gi0r[mt] = mfma16(hea[mt][kt], wf[0][kt], gi0r[mt]);
        gi0z[mt] = mfma16(hea[mt][kt], wf[1][kt], gi0z[mt]);
        gi0n[mt] = mfma16(hea[mt][kt], wf[2][kt], gi0n[mt]);
      }
    }
  }
  __syncthreads();
  stage_k128(smem + O_STAGE, dec_whh, 384, tid);
  __syncthreads();
  #pragma unroll
  for (int g = 0; g < 3; ++g)
    #pragma unroll
    for (int kt = 0; kt < 4; ++kt)
      wh[g][kt] = *(const short8*)(smem + O_STAGE + (g*128 + col)*SPITCH + kt*64 + quad*16);
  __syncthreads();
  // fc1/fc2 B-frags -> registers
  short8 f1f[2][4], f2f[8];
  stage_k128(smem + O_STAGE, fc1_w, 256, tid);
  __syncthreads();
  #pragma unroll
  for (int j = 0; j < 2; ++j)
    #pragma unroll
    for (int kt = 0; kt < 4; ++kt)
      f1f[j][kt] = *(const short8*)(smem + O_STAGE + (w*32 + j*16 + l15)*SPITCH + kt*64 + quad*16);
  __syncthreads();
  stage_k256(smem + O_STAGE, fc2_w, 64, tid);
  __syncthreads();
  #pragma unroll
  for (int kt = 0; kt < 8; ++kt)
    f2f[kt] = *(const short8*)(smem + O_STAGE + (nt2*16 + l15)*PITCH2 + kt*64 + quad*16);
  __syncthreads();
  // zero decoder h0 (buffer 1), reset hreg, present init
  for (int i = tid; i < HBUF/4; i += THREADS) ((unsigned*)(smem + O_H + HBUF))[i] = 0u;
  #pragma unroll
  for (int i = 0; i < 8; ++i) hreg[i] = 0.f;
  const int prow = tid / 6, pcol = tid - prow*6;
  float present = 0.f, fb3 = 0.f;
  if (tid < 192){
    present = past[(size_t)(b0 + prow)*768 + pcol*128 + 127];
    fb3 = fc3_b[pcol];
  }
  __syncthreads();

  // ================= decoder: 30 steps, 3 barriers each =================
  for (int s = 0; s < 30; ++s){
    const char* hr = smem + O_H + (1 - (s & 1)) * HBUF;
    char*       hw = smem + O_H + (s & 1) * HBUF;
    f32x4 accr[2], accz[2], accn2[2], gin[2];
    #pragma unroll
    for (int mt = 0; mt < 2; ++mt){
      if (s == 0){ accr[mt] = gi0r[mt]; accz[mt] = gi0z[mt]; gin[mt] = gi0n[mt]; }
      else       { accr[mt] = (f32x4){0.f,0.f,0.f,0.f}; accz[mt] = accr[mt]; gin[mt] = accr[mt]; }
      accn2[mt] = (f32x4){0.f,0.f,0.f,0.f};
    }
    {
      short8 ha[2][4];
      #pragma unroll
      for (int mt = 0; mt < 2; ++mt)
        #pragma unroll
        for (int kt = 0; kt < 4; ++kt)
          ha[mt][kt] = *(const short8*)(hr + (mt*16 + l15)*PITCH + kt*64 + quad*16);
      #pragma unroll
      for (int mt = 0; mt < 2; ++mt)
        #pragma unroll
        for (int kt = 0; kt < 4; ++kt){
          accr[mt]  = mfma16(ha[mt][kt], wh[0][kt], accr[mt]);
          accz[mt]  = mfma16(ha[mt][kt], wh[1][kt], accz[mt]);
          accn2[mt] = mfma16(ha[mt][kt], wh[2][kt], accn2[mt]);
        }
    }
    #pragma unroll
    for (int mt = 0; mt < 2; ++mt)
      #pragma unroll
      for (int r = 0; r < 4; ++r){
        float rg = sigm(accr[mt][r] + br_d);
        float zg = sigm(accz[mt][r] + bz_d);
        float ng = tanh_(gin[mt][r] + bin_d + rg*(accn2[mt][r] + bhn_d));
        hreg[mt*4 + r] = ng + zg*(hreg[mt*4 + r] - ng);
      }
    #pragma unroll
    for (int mt = 0; mt < 2; ++mt)
      #pragma unroll
      for (int r = 0; r < 4; ++r)
        *(unsigned short*)(hw + (mt*16 + quad*4 + r)*PITCH + col*2) = f2bf(hreg[mt*4 + r]);
    __syncthreads();   // D1: h(s+1) visible

    // fc1: (32x128)@(128x256) + relu -> a1 (B-frags in regs)
    {
      short8 hf[2][4];
      #pragma unroll
      for (int mt = 0; mt < 2; ++mt)
        #pragma unroll
        for (int kt = 0; kt < 4; ++kt)
          hf[mt][kt] = *(const short8*)(hw + (mt*16 + l15)*PITCH + kt*64 + quad*16);
      f32x4 a1a[2][2];
      #pragma unroll
      for (int mt = 0; mt < 2; ++mt)
        #pragma unroll
        for (int j = 0; j < 2; ++j) a1a[mt][j] = (f32x4){0.f,0.f,0.f,0.f};
      #pragma unroll
      for (int j = 0; j < 2; ++j)
        #pragma unroll
        for (int kt = 0; kt < 4; ++kt){
          a1a[0][j] = mfma16(hf[0][kt], f1f[j][kt], a1a[0][j]);
          a1a[1][j] = mfma16(hf[1][kt], f1f[j][kt], a1a[1][j]);
        }
      #pragma unroll
      for (int mt = 0; mt < 2; ++mt)
        #pragma unroll
        for (int j = 0; j < 2; ++j){
          float bb = j ? fb1b : fb1a;
          #pragma unroll
          for (int r = 0; r < 4; ++r)
            *(unsigned short*)(smem + O_A1D + (mt*16 + quad*4 + r)*PITCH2 +
                               (w*32 + j*16 + l15)*2) = f2bf(fmaxf(a1a[mt][j][r] + bb, 0.f));
        }
    }
    __syncthreads();   // D2: a1 visible

    // fc2: (32x256)@(256x64) -> a2 (B-frags in regs)
    {
      f32x4 a2a = (f32x4){0.f,0.f,0.f,0.f};
      #pragma unroll
      for (int kt = 0; kt < 8; ++kt){
        short8 a = *(const short8*)(smem + O_A1D + (mt2*16 + l15)*PITCH2 + kt*64 + quad*16);
        a2a = mfma16(a, f2f[kt], a2a);
      }
      #pragma unroll
      for (int r = 0; r < 4; ++r)
        *(unsigned short*)(smem + O_A2D + (mt2*16 + quad*4 + r)*144 + (nt2*16 + l15)*2) =
            f2bf(a2a[r] + fb2);
    }
    __syncthreads();   // D3: a2 visible

    // fc3 (6x64, VALU) + present accumulate + store
    if (tid < 192){
      float o = fb3;
      const float* w3 = (const float*)(smem + O_FC3W) + pcol*64;
      #pragma unroll
      for (int kc = 0; kc < 8; ++kc){
        short8 av = *(const short8*)(smem + O_A2D + prow*144 + kc*16);
        #pragma unroll
        for (int j = 0; j < 8; ++j)
          o += bf2f((unsigned short)av[j]) * w3[kc*8 + j];
      }
      present += o;
      out[(size_t)(b0 + prow)*180 + pcol*30 + s] = present;   // (B, 6, 30)
    }
    // fc3's a2 reads are protected by next step's D1+D2 barriers
  }
}

extern "C" void kernel_launch(void* const* d_in, const int* in_sizes, int n_in,
                              void* d_out, int out_size, void* d_ws, size_t ws_size,
                              hipStream_t stream) {
  (void)in_sizes; (void)n_in; (void)out_size; (void)d_ws; (void)ws_size;
  const float* past     = (const float*)d_in[0];
  const float* conv_w   = (const float*)d_in[1];
  const float* conv_b   = (const float*)d_in[2];
  const float* bn_gamma = (const float*)d_in[3];
  const float* bn_beta  = (const float*)d_in[4];
  const float* bn_mean  = (const float*)d_in[5];
  const float* bn_var   = (const float*)d_in[6];
  const float* enc_wih  = (const float*)d_in[7];
  const float* enc_whh  = (const float*)d_in[8];
  const float* enc_bih  = (const float*)d_in[9];
  const float* enc_bhh  = (const float*)d_in[10];
  const float* dec_wih  = (const float*)d_in[11];
  const float* dec_whh  = (const float*)d_in[12];
  const float* dec_bih  = (const float*)d_in[13];
  const float* dec_bhh  = (const float*)d_in[14];
  const float* fc1_w    = (const float*)d_in[15];
  const float* fc1_b    = (const float*)d_in[16];
  const float* fc2_w    = (const float*)d_in[17];
  const float* fc2_b    = (const float*)d_in[18];
  const float* fc3_w    = (const float*)d_in[19];
  const float* fc3_b    = (const float*)d_in[20];

  hipFuncSetAttribute((const void*)gru_fused,
                      hipFuncAttributeMaxDynamicSharedMemorySize, LDS_TOTAL);

  gru_fused<<<NBLK, THREADS, LDS_TOTAL, stream>>>(
      past, conv_w, conv_b, bn_gamma, bn_beta, bn_mean, bn_var,
      enc_wih, enc_whh, enc_bih, enc_bhh,
      dec_wih, dec_whh, dec_bih, dec_bhh,
      fc1_w, fc1_b, fc2_w, fc2_b, fc3_w, fc3_b,
      (float*)d_out);
}

// Round 5
// 465.783 us; speedup vs baseline: 1.6841x; 1.0132x over previous
//
#include <hip/hip_runtime.h>

#define DI __device__ __forceinline__

typedef __attribute__((ext_vector_type(8))) short short8;
typedef __attribute__((ext_vector_type(4))) float f32x4;

constexpr int THREADS = 512;           // 8 waves
constexpr int ROWS    = 32;            // batch rows per block
constexpr int NBLK    = 8192 / ROWS;   // 256 blocks = 256 CUs
constexpr int PITCH   = 272;           // K=128 bf16 rows; 272%128==16 -> b128 reads conflict-free
constexpr int PITCH2  = 528;           // K=256 bf16 rows; 528%128==16 -> conflict-free
constexpr int SPITCH  = 256;           // one-time staging pitch (conflicts don't matter there)

// ---- LDS layout (bytes) ----
constexpr int O_STAGE = 0;        // 98304 = 384*256: staging; then past_l (50688) in encoder
constexpr int O_PATCH = 98304;    // 10240: patch_all 128 rows x 80B (4 steps x 32 rows)
constexpr int O_XALL  = 108544;   // 34816: x_all 128 rows x 272B (4 steps x 32 rows)
constexpr int O_H     = 143360;   // 2 x 8704 hidden-state double buffer
constexpr int HBUF    = 8704;
constexpr int O_FC3W  = 160768;   // 1536: fc3 weights f32
constexpr int LDS_TOTAL = 162304; // <= 163840
// decoder aliases (stage/patch/x_all dead during decoder steps)
constexpr int O_A1D   = 98304;    // 16896: a1 (32 x 528)
constexpr int O_W32   = 115200;   // 8448: fused (fc3@fc2) weights, bf16 B-layout 16 x 528
constexpr int O_B32   = 123648;   // 24: fused bias f32 (6)

// HW packed f32->bf16 (RNE), 1 instr; no builtin on gfx950 -> inline asm.
DI unsigned cvtpk2(float lo, float hi){
  unsigned r;
  asm("v_cvt_pk_bf16_f32 %0, %1, %2" : "=v"(r) : "v"(lo), "v"(hi));
  return r;
}
DI unsigned short f2bf(float f){ return (unsigned short)cvtpk2(f, f); }
DI float bf2f(unsigned short u){
  union { unsigned u; float f; } v; v.u = ((unsigned)u) << 16;
  return v.f;
}
// rcp-based activations (v_rcp_f32, ~1 ulp); saturation correct (rcp(inf)=0).
DI float sigm(float x){ return __builtin_amdgcn_rcpf(1.f + __expf(-x)); }
DI float tanh_(float x){ return 2.f * __builtin_amdgcn_rcpf(1.f + __expf(-2.f * x)) - 1.f; }
DI f32x4 mfma16(short8 a, short8 b, f32x4 c){
  return __builtin_amdgcn_mfma_f32_16x16x32_bf16(a, b, c, 0, 0, 0);
}

// one-time: stage (nrows x 128) f32 -> bf16 LDS, pitch SPITCH
DI void stage_k128(char* dst, const float* __restrict__ src, int nrows, int tid){
  const int total = nrows * 32;
  for (int i = tid; i < total; i += THREADS){
    float4 v = ((const float4*)src)[i];
    int e = i << 2;
    int n = e >> 7, k = e & 127;
    *(uint2*)(dst + n * SPITCH + k * 2) = make_uint2(cvtpk2(v.x, v.y), cvtpk2(v.z, v.w));
  }
}

__global__ void __launch_bounds__(THREADS, 2)
gru_fused(const float* __restrict__ past,
          const float* __restrict__ conv_w, const float* __restrict__ conv_b,
          const float* __restrict__ bn_gamma, const float* __restrict__ bn_beta,
          const float* __restrict__ bn_mean, const float* __restrict__ bn_var,
          const float* __restrict__ enc_wih, const float* __restrict__ enc_whh,
          const float* __restrict__ enc_bih, const float* __restrict__ enc_bhh,
          const float* __restrict__ dec_wih, const float* __restrict__ dec_whh,
          const float* __restrict__ dec_bih, const float* __restrict__ dec_bhh,
          const float* __restrict__ fc1_w, const float* __restrict__ fc1_b,
          const float* __restrict__ fc2_w, const float* __restrict__ fc2_b,
          const float* __restrict__ fc3_w, const float* __restrict__ fc3_b,
          float* __restrict__ out)
{
  extern __shared__ char smem[];
  const int tid  = threadIdx.x;
  const int lane = tid & 63, w = tid >> 6;        // wave w owns gate-col slice w*16..w*16+15
  const int l15  = lane & 15, quad = lane >> 4;
  const int b0   = blockIdx.x * ROWS;
  const int col  = w * 16 + l15;

  // ---- per-thread bias registers ----
  const float br_e  = enc_bih[col]       + enc_bhh[col];
  const float bz_e  = enc_bih[128 + col] + enc_bhh[128 + col];
  const float bin_e = enc_bih[256 + col];
  const float bhn_e = enc_bhh[256 + col];
  const float br_d  = dec_bih[col]       + dec_bhh[col];
  const float bz_d  = dec_bih[128 + col] + dec_bhh[128 + col];
  const float bin_d = dec_bih[256 + col];
  const float bhn_d = dec_bhh[256 + col];
  const float cb_t  = conv_b[col];
  const float s_bn  = bn_gamma[0] * rsqrtf(bn_var[0] + 1e-5f);
  const float o_bn  = bn_beta[0] - bn_mean[0] * s_bn;
  const float fb1a  = fc1_b[w * 32 + l15];
  const float fb1b  = fc1_b[w * 32 + 16 + l15];

  // ---- zero h double buffer ----
  for (int i = tid; i < 2*HBUF/4; i += THREADS) ((unsigned*)(smem + O_H))[i] = 0u;

  // ---- stage encoder weights once, pull B-fragments to registers ----
  short8 wf[3][4], wh[3][4];
  stage_k128(smem + O_STAGE, enc_wih, 384, tid);
  __syncthreads();
  #pragma unroll
  for (int g = 0; g < 3; ++g)
    #pragma unroll
    for (int kt = 0; kt < 4; ++kt)
      wf[g][kt] = *(const short8*)(smem + O_STAGE + (g*128 + col)*SPITCH + kt*64 + quad*16);
  __syncthreads();
  stage_k128(smem + O_STAGE, enc_whh, 384, tid);
  __syncthreads();
  #pragma unroll
  for (int g = 0; g < 3; ++g)
    #pragma unroll
    for (int kt = 0; kt < 4; ++kt)
      wh[g][kt] = *(const short8*)(smem + O_STAGE + (g*128 + col)*SPITCH + kt*64 + quad*16);
  __syncthreads();

  // ---- conv weights: cwT[oc][k=c*3+kk] bf16, 80B rows, K padded 18->32 ----
  for (int i = tid; i < 2560; i += THREADS) ((unsigned*)(smem + O_STAGE))[i] = 0u;
  __syncthreads();
  for (int i = tid; i < 2304; i += THREADS){
    int oc = i / 18, kk = i - oc * 18;
    *(unsigned short*)(smem + O_STAGE + oc*80 + kk*2) = f2bf(conv_w[i]);
  }
  __syncthreads();
  const short8 cwf = *(const short8*)(smem + O_STAGE + col*80 + quad*16);
  __syncthreads();

  // ---- past -> LDS bf16: past_l[m][c][tpos 0..131] (shift +1, zero padded) ----
  for (int i = tid; i < 12672; i += THREADS) ((unsigned*)(smem + O_STAGE))[i] = 0u;
  __syncthreads();
  for (int i4 = tid; i4 < 6144; i4 += THREADS){
    int m = i4 / 192, rem = i4 - m*192, c = rem >> 5, t4 = (rem & 31) << 2;
    float4 v = *(const float4*)(past + (size_t)(b0 + m)*768 + c*128 + t4);
    unsigned short* dst = (unsigned short*)(smem + O_STAGE + ((m*6 + c)*132 + t4 + 1)*2);
    dst[0] = f2bf(v.x); dst[1] = f2bf(v.y); dst[2] = f2bf(v.z); dst[3] = f2bf(v.w);
  }
  for (int i = tid; i < 384; i += THREADS) ((float*)(smem + O_FC3W))[i] = fc3_w[i];
  __syncthreads();

  // patch-build constants: entry e -> (m, r18=(c,kk)); each thread covers e0 (+e1 if tid<64)
  const int e0 = tid;
  const int m0 = e0 / 18, r0 = e0 - m0*18, c0 = r0 / 3, k0 = r0 - c0*3;
  const int e1 = tid + 512;
  const int m1 = e1 / 18, r1 = e1 - m1*18, c1 = r1 / 3, k1 = r1 - c1*3;

  // build patch_all rows tc*32+m for steps t0..t0+3 (one entry)
  auto patch_entry = [&](int t0, int m, int r18, int c, int k){
    int base = (m*6 + c)*132 + t0 + k;            // short index into past_l
    const unsigned* pl = (const unsigned*)(smem + O_STAGE);
    unsigned w0 = pl[base >> 1], w1 = pl[(base >> 1) + 1], w2 = pl[(base >> 1) + 2];
    int sh = (base & 1) * 16;
    unsigned long long lo = (unsigned long long)w0 | ((unsigned long long)w1 << 32);
    unsigned long long hi = (unsigned long long)w1 | ((unsigned long long)w2 << 32);
    unsigned a01 = (unsigned)(lo >> sh);          // shorts t0+k, t0+k+1
    unsigned a23 = (unsigned)(hi >> sh);          // shorts t0+k+2, t0+k+3
    char* pb = smem + O_PATCH + m*80 + r18*2;
    *(unsigned short*)(pb)          = (unsigned short)(a01 & 0xffff);
    *(unsigned short*)(pb + 2560)   = (unsigned short)(a01 >> 16);
    *(unsigned short*)(pb + 5120)   = (unsigned short)(a23 & 0xffff);
    *(unsigned short*)(pb + 7680)   = (unsigned short)(a23 >> 16);
  };
  auto patchA1 = [&](int t0){
    patch_entry(t0, m0, r0, c0, k0);
    if (e1 < 576) patch_entry(t0, m1, r1, c1, k1);
  };

  // ---- accumulator/state registers ----
  f32x4 gi_f[4][2][3];                  // f32 gi ring for 4 steps: [tc][mt][gate] (96 regs; budget 256)
  float hreg[8];
  #pragma unroll
  for (int i = 0; i < 8; ++i) hreg[i] = 0.f;

  // A2: conv as M=128 GEMM + bias/relu/bn -> x_all (reads patch, overwrites x_all)
  auto conv_block = [&](){
    #pragma unroll
    for (int mt8 = 0; mt8 < 8; ++mt8){
      short8 pa = *(const short8*)(smem + O_PATCH + (mt8*16 + l15)*80 + quad*16);
      f32x4 cc = (f32x4){0.f,0.f,0.f,0.f};
      cc = mfma16(pa, cwf, cc);
      #pragma unroll
      for (int r = 0; r < 4; ++r){
        int mrow = mt8*16 + quad*4 + r;
        float vx = s_bn * fmaxf(cc[r] + cb_t, 0.f) + o_bn;
        *(unsigned short*)(smem + O_XALL + mrow*PITCH + col*2) = f2bf(vx);
      }
    }
  };
  // A3 unit: gi for (tc, mt) from x_all -> gi_f slot (stays f32 in regs)
  auto gi_unit = [&](int tc, int mt){
    short8 a[4];
    #pragma unroll
    for (int kt = 0; kt < 4; ++kt)
      a[kt] = *(const short8*)(smem + O_XALL + ((tc*2 + mt)*16 + l15)*PITCH + kt*64 + quad*16);
    f32x4 g0 = (f32x4){0.f,0.f,0.f,0.f}, g1 = g0, g2 = g0;
    #pragma unroll
    for (int kt = 0; kt < 4; ++kt){
      g0 = mfma16(a[kt], wf[0][kt], g0);
      g1 = mfma16(a[kt], wf[1][kt], g1);
      g2 = mfma16(a[kt], wf[2][kt], g2);
    }
    gi_f[tc][mt][0] = g0;
    gi_f[tc][mt][1] = g1;
    gi_f[tc][mt][2] = g2;
  };
  // one recurrent step (consumes gi_f[tc]; no barrier inside); tc passed as literal
  auto step_body = [&](int t, int tc){
    const char* hr = smem + O_H + (t & 1) * HBUF;
    char*       hw = smem + O_H + ((t + 1) & 1) * HBUF;
    f32x4 accr[2], accz[2], accn2[2], gin[2];
    #pragma unroll
    for (int mt = 0; mt < 2; ++mt){
      accr[mt]  = gi_f[tc][mt][0];
      accz[mt]  = gi_f[tc][mt][1];
      gin[mt]   = gi_f[tc][mt][2];
      accn2[mt] = (f32x4){0.f,0.f,0.f,0.f};
    }
    short8 ha[2][4];
    #pragma unroll
    for (int mt = 0; mt < 2; ++mt)
      #pragma unroll
      for (int kt = 0; kt < 4; ++kt)
        ha[mt][kt] = *(const short8*)(hr + (mt*16 + l15)*PITCH + kt*64 + quad*16);
    #pragma unroll
    for (int mt = 0; mt < 2; ++mt)
      #pragma unroll
      for (int kt = 0; kt < 4; ++kt){
        accr[mt]  = mfma16(ha[mt][kt], wh[0][kt], accr[mt]);
        accz[mt]  = mfma16(ha[mt][kt], wh[1][kt], accz[mt]);
        accn2[mt] = mfma16(ha[mt][kt], wh[2][kt], accn2[mt]);
      }
    #pragma unroll
    for (int mt = 0; mt < 2; ++mt)
      #pragma unroll
      for (int r = 0; r < 4; ++r){
        float rg = sigm(accr[mt][r] + br_e);
        float zg = sigm(accz[mt][r] + bz_e);
        float ng = tanh_(gin[mt][r] + bin_e + rg*(accn2[mt][r] + bhn_e));
        hreg[mt*4 + r] = ng + zg*(hreg[mt*4 + r] - ng);
      }
    #pragma unroll
    for (int mt = 0; mt < 2; ++mt)
      #pragma unroll
      for (int r = 0; r < 4; ++r)
        *(unsigned short*)(hw + (mt*16 + quad*4 + r)*PITCH + col*2) = f2bf(hreg[mt*4 + r]);
  };

  // ================= encoder: software-pipelined =================
  patchA1(0);
  __syncthreads();
  conv_block();
  __syncthreads();
  #pragma unroll
  for (int tc = 0; tc < 4; ++tc){ gi_unit(tc, 0); gi_unit(tc, 1); }
  patchA1(4);        // safe: all patch reads (conv of chunk 0) completed before last barrier
  __syncthreads();

  // Main loop: chunk c consumes gi(c) while producing x_all/gi for c+1 and patch for c+2.
  for (int c = 0; c < 32; ++c){
    const int t0 = c * 4;
    const bool prod = (c < 31);
    step_body(t0 + 0, 0);
    if (prod) conv_block();                       // x_all <- chunk c+1
    __syncthreads();
    step_body(t0 + 1, 1);
    if (prod){ gi_unit(0,0); gi_unit(0,1); gi_unit(1,0); }
    __syncthreads();
    step_body(t0 + 2, 2);
    if (prod){ gi_unit(1,1); gi_unit(2,0); gi_unit(2,1); }
    __syncthreads();
    step_body(t0 + 3, 3);
    if (prod){ gi_unit(3,0); gi_unit(3,1); if (c < 30) patchA1(t0 + 8); }
    __syncthreads();
  }
  // after t=127: h_enc lives in hbuf[0] (and hreg)

  // ================= decoder init =================
  // dec_wih frags + gi0 = h_enc @ dec_wih^T
  stage_k128(smem + O_STAGE, dec_wih, 384, tid);
  __syncthreads();
  #pragma unroll
  for (int g = 0; g < 3; ++g)
    #pragma unroll
    for (int kt = 0; kt < 4; ++kt)
      wf[g][kt] = *(const short8*)(smem + O_STAGE + (g*128 + col)*SPITCH + kt*64 + quad*16);
  f32x4 gi0r[2], gi0z[2], gi0n[2];
  {
    short8 hea[2][4];
    #pragma unroll
    for (int mt = 0; mt < 2; ++mt)
      #pragma unroll
      for (int kt = 0; kt < 4; ++kt)
        hea[mt][kt] = *(const short8*)(smem + O_H + (mt*16 + l15)*PITCH + kt*64 + quad*16);
    #pragma unroll
    for (int mt = 0; mt < 2; ++mt){
      gi0r[mt] = (f32x4){0.f,0.f,0.f,0.f}; gi0z[mt] = gi0r[mt]; gi0n[mt] = gi0r[mt];
      #pragma unroll
      for (int kt = 0; kt < 4; ++kt){
        gi0r[mt] = mfma16(hea[mt][kt], wf[0][kt], gi0r[mt]);
        gi0z[mt] = mfma16(hea[mt][kt], wf[1][kt], gi0z[mt]);
        gi0n[mt] = mfma16(hea[mt][kt], wf[2][kt], gi0n[mt]);
      }
    }
  }
  __syncthreads();
  stage_k128(smem + O_STAGE, dec_whh, 384, tid);
  __syncthreads();
  #pragma unroll
  for (int g = 0; g < 3; ++g)
    #pragma unroll
    for (int kt = 0; kt < 4; ++kt)
      wh[g][kt] = *(const short8*)(smem + O_STAGE + (g*128 + col)*SPITCH + kt*64 + quad*16);
  __syncthreads();
  // fc1 B-frags -> registers
  short8 f1f[2][4];
  stage_k128(smem + O_STAGE, fc1_w, 256, tid);
  __syncthreads();
  #pragma unroll
  for (int j = 0; j < 2; ++j)
    #pragma unroll
    for (int kt = 0; kt < 4; ++kt)
      f1f[j][kt] = *(const short8*)(smem + O_STAGE + (w*32 + j*16 + l15)*SPITCH + kt*64 + quad*16);
  __syncthreads();

  // ---- build fused W32 = fc3_w @ fc2_w (6x256) as bf16 B-frags (16 rows, PITCH2), + b32 ----
  for (int i = tid; i < 2112; i += THREADS) ((unsigned*)(smem + O_W32))[i] = 0u;
  __syncthreads();
  {
    const int kk = tid & 255, wn = (tid >> 8) * 3;
    const float* f3p = (const float*)(smem + O_FC3W);
    float o0 = 0.f, o1 = 0.f, o2 = 0.f;
    for (int j = 0; j < 64; ++j){
      float cv = fc2_w[j*256 + kk];
      o0 += f3p[(wn+0)*64 + j] * cv;
      o1 += f3p[(wn+1)*64 + j] * cv;
      o2 += f3p[(wn+2)*64 + j] * cv;
    }
    *(unsigned short*)(smem + O_W32 + (wn+0)*PITCH2 + kk*2) = f2bf(o0);
    *(unsigned short*)(smem + O_W32 + (wn+1)*PITCH2 + kk*2) = f2bf(o1);
    *(unsigned short*)(smem + O_W32 + (wn+2)*PITCH2 + kk*2) = f2bf(o2);
    if (tid < 6){
      float ob = fc3_b[tid];
      for (int j = 0; j < 64; ++j) ob += f3p[tid*64 + j] * fc2_b[j];
      ((float*)(smem + O_B32))[tid] = ob;
    }
  }
  // zero decoder h0 (buffer 1), reset hreg
  for (int i = tid; i < HBUF/4; i += THREADS) ((unsigned*)(smem + O_H + HBUF))[i] = 0u;
  #pragma unroll
  for (int i = 0; i < 8; ++i) hreg[i] = 0.f;
  __syncthreads();
  // present/b32 registers (waves 0-1, lanes l15<6 own (rows w*16+quad*4+r, col l15))
  float pres[4] = {0.f, 0.f, 0.f, 0.f};
  float b32v = 0.f;
  if (w < 2 && l15 < 6){
    b32v = ((const float*)(smem + O_B32))[l15];
    #pragma unroll
    for (int r = 0; r < 4; ++r)
      pres[r] = past[(size_t)(b0 + w*16 + quad*4 + r)*768 + l15*128 + 127];
  }

  // ================= decoder: 30 steps, 2 barriers each =================
  for (int s = 0; s < 30; ++s){
    const char* hr = smem + O_H + (1 - (s & 1)) * HBUF;
    char*       hw = smem + O_H + (s & 1) * HBUF;
    f32x4 accr[2], accz[2], accn2[2], gin[2];
    #pragma unroll
    for (int mt = 0; mt < 2; ++mt){
      if (s == 0){ accr[mt] = gi0r[mt]; accz[mt] = gi0z[mt]; gin[mt] = gi0n[mt]; }
      else       { accr[mt] = (f32x4){0.f,0.f,0.f,0.f}; accz[mt] = accr[mt]; gin[mt] = accr[mt]; }
      accn2[mt] = (f32x4){0.f,0.f,0.f,0.f};
    }
    {
      short8 ha[2][4];
      #pragma unroll
      for (int mt = 0; mt < 2; ++mt)
        #pragma unroll
        for (int kt = 0; kt < 4; ++kt)
          ha[mt][kt] = *(const short8*)(hr + (mt*16 + l15)*PITCH + kt*64 + quad*16);
      #pragma unroll
      for (int mt = 0; mt < 2; ++mt)
        #pragma unroll
        for (int kt = 0; kt < 4; ++kt){
          accr[mt]  = mfma16(ha[mt][kt], wh[0][kt], accr[mt]);
          accz[mt]  = mfma16(ha[mt][kt], wh[1][kt], accz[mt]);
          accn2[mt] = mfma16(ha[mt][kt], wh[2][kt], accn2[mt]);
        }
    }
    #pragma unroll
    for (int mt = 0; mt < 2; ++mt)
      #pragma unroll
      for (int r = 0; r < 4; ++r){
        float rg = sigm(accr[mt][r] + br_d);
        float zg = sigm(accz[mt][r] + bz_d);
        float ng = tanh_(gin[mt][r] + bin_d + rg*(accn2[mt][r] + bhn_d));
        hreg[mt*4 + r] = ng + zg*(hreg[mt*4 + r] - ng);
      }
    #pragma unroll
    for (int mt = 0; mt < 2; ++mt)
      #pragma unroll
      for (int r = 0; r < 4; ++r)
        *(unsigned short*)(hw + (mt*16 + quad*4 + r)*PITCH + col*2) = f2bf(hreg[mt*4 + r]);
    __syncthreads();   // D1: h(s+1) visible

    // fc1: (32x128)@(128x256) + relu -> a1 (B-frags in regs)
    {
      short8 hf[2][4];
      #pragma unroll
      for (int mt = 0; mt < 2; ++mt)
        #pragma unroll
        for (int kt = 0; kt < 4; ++kt)
          hf[mt][kt] = *(const short8*)(hw + (mt*16 + l15)*PITCH + kt*64 + quad*16);
      f32x4 a1a[2][2];
      #pragma unroll
      for (int mt = 0; mt < 2; ++mt)
        #pragma unroll
        for (int j = 0; j < 2; ++j) a1a[mt][j] = (f32x4){0.f,0.f,0.f,0.f};
      #pragma unroll
      for (int j = 0; j < 2; ++j)
        #pragma unroll
        for (int kt = 0; kt < 4; ++kt){
          a1a[0][j] = mfma16(hf[0][kt], f1f[j][kt], a1a[0][j]);
          a1a[1][j] = mfma16(hf[1][kt], f1f[j][kt], a1a[1][j]);
        }
      #pragma unroll
      for (int mt = 0; mt < 2; ++mt)
        #pragma unroll
        for (int j = 0; j < 2; ++j){
          float bb = j ? fb1b : fb1a;
          #pragma unroll
          for (int r = 0; r < 4; ++r)
            *(unsigned short*)(smem + O_A1D + (mt*16 + quad*4 + r)*PITCH2 +
                               (w*32 + j*16 + l15)*2) = f2bf(fmaxf(a1a[mt][j][r] + bb, 0.f));
        }
    }
    __syncthreads();   // D2: a1 visible

    // fused fc2+fc3: out6 = a1 @ W32^T + b32; waves 0-1 only (mt = w), no barrier.
    // a1 reads here are ordered against next step's a1 writes by D1 (program order within
    // waves 0-1; other waves write a1 only after passing D1).
    if (w < 2){
      f32x4 acc = (f32x4){0.f,0.f,0.f,0.f};
      #pragma unroll
      for (int kt = 0; kt < 8; ++kt){
        short8 a   = *(const short8*)(smem + O_A1D + (w*16 + l15)*PITCH2 + kt*64 + quad*16);
        short8 bfr = *(const short8*)(smem + O_W32 + l15*PITCH2 + kt*64 + quad*16);
        acc = mfma16(a, bfr, acc);
      }
      if (l15 < 6){
        #pragma unroll
        for (int r = 0; r < 4; ++r){
          pres[r] += acc[r] + b32v;
          out[(size_t)(b0 + w*16 + quad*4 + r)*180 + l15*30 + s] = pres[r];   // (B, 6, 30)
        }
      }
    }
  }
}

extern "C" void kernel_launch(void* const* d_in, const int* in_sizes, int n_in,
                              void* d_out, int out_size, void* d_ws, size_t ws_size,
                              hipStream_t stream) {
  (void)in_sizes; (void)n_in; (void)out_size; (void)d_ws; (void)ws_size;
  const float* past     = (const float*)d_in[0];
  const float* conv_w   = (const float*)d_in[1];
  const float* conv_b   = (const float*)d_in[2];
  const float* bn_gamma = (const float*)d_in[3];
  const float* bn_beta  = (const float*)d_in[4];
  const float* bn_mean  = (const float*)d_in[5];
  const float* bn_var   = (const float*)d_in[6];
  const float* enc_wih  = (const float*)d_in[7];
  const float* enc_whh  = (const float*)d_in[8];
  const float* enc_bih  = (const float*)d_in[9];
  const float* enc_bhh  = (const float*)d_in[10];
  const float* dec_wih  = (const float*)d_in[11];
  const float* dec_whh  = (const float*)d_in[12];
  const float* dec_bih  = (const float*)d_in[13];
  const float* dec_bhh  = (const float*)d_in[14];
  const float* fc1_w    = (const float*)d_in[15];
  const float* fc1_b    = (const float*)d_in[16];
  const float* fc2_w    = (const float*)d_in[17];
  const float* fc2_b    = (const float*)d_in[18];
  const float* fc3_w    = (const float*)d_in[19];
  const float* fc3_b    = (const float*)d_in[20];

  hipFuncSetAttribute((const void*)gru_fused,
                      hipFuncAttributeMaxDynamicSharedMemorySize, LDS_TOTAL);

  gru_fused<<<NBLK, THREADS, LDS_TOTAL, stream>>>(
      past, conv_w, conv_b, bn_gamma, bn_beta, bn_mean, bn_var,
      enc_wih, enc_whh, enc_bih, enc_bhh,
      dec_wih, dec_whh, dec_bih, dec_bhh,
      fc1_w, fc1_b, fc2_w, fc2_b, fc3_w, fc3_b,
      (float*)d_out);
}